// Round 1
// baseline (2796.630 us; speedup 1.0000x reference)
//
#include <hip/hip_runtime.h>
#include <hip/hip_bf16.h>

// Problem constants (from the reference)
constexpr int NUM_B   = 32;
constexpr int HW0 = 60 * 80;   // 4800
constexpr int HW1 = 30 * 40;   // 1200
constexpr int HW2 = 15 * 20;   // 300
constexpr int A_TOTAL = HW0 + HW1 + HW2;          // 6300
constexpr int SEG_TOTAL = NUM_B * A_TOTAL;        // 201600
constexpr int C_CH = 7;                           // reg4 + obj1 + cls2

// ---------------------------------------------------------------------------
// Scatter: one thread per point; accumulate sums[seg][7] and counts[seg]
// via global atomics. seg = b*(H*W) + row*W + col (scale-local), the caller
// passes scale-offset sums/counts pointers.
// ---------------------------------------------------------------------------
__global__ void scatter_kernel(const float* __restrict__ cls,
                               const float* __restrict__ reg,
                               const float* __restrict__ obj,
                               const float* __restrict__ pos,
                               const int*   __restrict__ batch,
                               int n, int W, int H, float stride,
                               float* __restrict__ sums,    // [B*H*W][7]
                               float* __restrict__ counts)  // [B*H*W]
{
    int i   = blockIdx.x * blockDim.x + threadIdx.x;
    int gsz = gridDim.x * blockDim.x;
    for (; i < n; i += gsz) {
        float2 p = reinterpret_cast<const float2*>(pos)[i];
        int b = batch[i];
        // exactly the reference binning: IEEE f32 divide, trunc-to-int, clip
        int col = (int)(p.x / stride);
        int row = (int)(p.y / stride);
        col = min(max(col, 0), W - 1);
        row = min(max(row, 0), H - 1);
        int seg = b * (H * W) + row * W + col;

        float4 r = reinterpret_cast<const float4*>(reg)[i];
        float  o = obj[i];
        float2 c = reinterpret_cast<const float2*>(cls)[i];

        float* sb = sums + (size_t)seg * C_CH;
        atomicAdd(sb + 0, r.x);
        atomicAdd(sb + 1, r.y);
        atomicAdd(sb + 2, r.z);
        atomicAdd(sb + 3, r.w);
        atomicAdd(sb + 4, o);
        atomicAdd(sb + 5, c.x);
        atomicAdd(sb + 6, c.y);
        atomicAdd(counts + seg, 1.0f);
    }
}

// ---------------------------------------------------------------------------
// Finalize: one thread per (b, anchor). mean -> sigmoid(ch4..6) -> YOLOX decode.
// Output layout: out[b][a][c], c fastest (f32).
// ---------------------------------------------------------------------------
__global__ void finalize_kernel(const float* __restrict__ sums,
                                const float* __restrict__ counts,
                                float* __restrict__ out)
{
    int t = blockIdx.x * blockDim.x + threadIdx.x;
    if (t >= SEG_TOTAL) return;
    int b = t / A_TOTAL;
    int a = t - b * A_TOTAL;

    int hw, Wl, segbase;
    float stride;
    if (a < HW0) {
        hw = a;             Wl = 80; stride = 3.0f;
        segbase = b * HW0;                      // scale0 region starts at 0
    } else if (a < HW0 + HW1) {
        hw = a - HW0;       Wl = 40; stride = 6.0f;
        segbase = NUM_B * HW0 + b * HW1;
    } else {
        hw = a - HW0 - HW1; Wl = 20; stride = 12.0f;
        segbase = NUM_B * (HW0 + HW1) + b * HW2;
    }
    int seg = segbase + hw;
    int row = hw / Wl;
    int col = hw - row * Wl;

    const float* sb = sums + (size_t)seg * C_CH;
    float cnt = counts[seg];
    float inv = 1.0f / fmaxf(cnt, 1.0f);

    float m0 = sb[0] * inv;
    float m1 = sb[1] * inv;
    float m2 = sb[2] * inv;
    float m3 = sb[3] * inv;
    float m4 = sb[4] * inv;
    float m5 = sb[5] * inv;
    float m6 = sb[6] * inv;

    float x = (m0 + (float)col) * stride;
    float y = (m1 + (float)row) * stride;
    float w = expf(fminf(m2, 10.0f)) * stride;
    float h = expf(fminf(m3, 10.0f)) * stride;
    float s4 = 1.0f / (1.0f + expf(-m4));
    float s5 = 1.0f / (1.0f + expf(-m5));
    float s6 = 1.0f / (1.0f + expf(-m6));

    float* ob = out + (size_t)t * C_CH;
    ob[0] = x; ob[1] = y; ob[2] = w; ob[3] = h;
    ob[4] = s4; ob[5] = s5; ob[6] = s6;
}

// ---------------------------------------------------------------------------
extern "C" void kernel_launch(void* const* d_in, const int* in_sizes, int n_in,
                              void* d_out, int out_size, void* d_ws, size_t ws_size,
                              hipStream_t stream)
{
    float* sums   = reinterpret_cast<float*>(d_ws);           // [SEG_TOTAL][7]
    float* counts = sums + (size_t)SEG_TOTAL * C_CH;          // [SEG_TOTAL]

    // zero accumulators every call (harness does not re-poison between replays)
    hipMemsetAsync(d_ws, 0, (size_t)SEG_TOTAL * (C_CH + 1) * sizeof(float), stream);

    const int   Ws[3]      = {80, 40, 20};
    const int   Hs[3]      = {60, 30, 15};
    const float strides[3] = {3.0f, 6.0f, 12.0f};
    const int   segoff[3]  = {0, NUM_B * HW0, NUM_B * (HW0 + HW1)};

    for (int s = 0; s < 3; ++s) {
        const float* cls   = reinterpret_cast<const float*>(d_in[5 * s + 0]);
        const float* reg   = reinterpret_cast<const float*>(d_in[5 * s + 1]);
        const float* obj   = reinterpret_cast<const float*>(d_in[5 * s + 2]);
        const float* pos   = reinterpret_cast<const float*>(d_in[5 * s + 3]);
        const int*   batch = reinterpret_cast<const int*>(d_in[5 * s + 4]);
        int n = in_sizes[5 * s + 2];   // obj has 1 element per point

        int blocks = (n + 255) / 256;
        if (blocks > 2048) blocks = 2048;
        scatter_kernel<<<blocks, 256, 0, stream>>>(
            cls, reg, obj, pos, batch, n, Ws[s], Hs[s], strides[s],
            sums + (size_t)segoff[s] * C_CH, counts + segoff[s]);
    }

    int fblocks = (SEG_TOTAL + 255) / 256;
    finalize_kernel<<<fblocks, 256, 0, stream>>>(sums, counts,
                                                 reinterpret_cast<float*>(d_out));
}

// Round 2
// 592.764 us; speedup vs baseline: 4.7180x; 4.7180x over previous
//
#include <hip/hip_runtime.h>
#include <hip/hip_bf16.h>

// ---------------------------------------------------------------------------
// Problem constants
// ---------------------------------------------------------------------------
#define NUM_B    32
#define A_TOTAL  6300
#define SEG_TOTAL 201600
#define NTILES   255          // 150 + 75 + 30
#define NBLK0    512
#define NBLK1    256
#define NBLK2    128
#define NBLK_TOT 896

struct Ptrs {
    const float* cls; const float* reg; const float* obj;
    const float* pos; const int* batch;
    int n, chunk;
};
struct Args { Ptrs s[3]; };

__device__ __forceinline__ void scale_consts(int s, int& HW, int& W, int& H,
                                             float& st, int& tps, int& nt,
                                             int& toff, int& segoff, int& aoff)
{
    if (s == 0)      { HW=4800; W=80; H=60; st=3.f;  tps=1024; nt=150; toff=0;   segoff=0;      aoff=0;    }
    else if (s == 1) { HW=1200; W=40; H=30; st=6.f;  tps=512;  nt=75;  toff=150; segoff=153600; aoff=4800; }
    else             { HW=300;  W=20; H=15; st=12.f; tps=320;  nt=30;  toff=225; segoff=192000; aoff=6000; }
}

__device__ __forceinline__ int block_scale(int bid, int& lb)
{
    if (bid < NBLK0)         { lb = bid;                   return 0; }
    if (bid < NBLK0 + NBLK1) { lb = bid - NBLK0;           return 1; }
    lb = bid - (NBLK0 + NBLK1);                            return 2;
}

// ---------------------------------------------------------------------------
// Pass 1: per-tile histogram (LDS-privatized)
// ---------------------------------------------------------------------------
__global__ __launch_bounds__(256) void p1_count(Args a, int* __restrict__ tile_count)
{
    __shared__ int hist[160];
    int lb; int s = block_scale(blockIdx.x, lb);
    int HW,W,H,tps,nt,toff,segoff,aoff; float st;
    scale_consts(s,HW,W,H,st,tps,nt,toff,segoff,aoff);
    const Ptrs& P = a.s[s];

    for (int t = threadIdx.x; t < nt; t += 256) hist[t] = 0;
    __syncthreads();

    int start = lb * P.chunk;
    int end   = min(start + P.chunk, P.n);
    const float2* pos = reinterpret_cast<const float2*>(P.pos);
    for (int i = start + (int)threadIdx.x; i < end; i += 256) {
        float2 p = pos[i];
        int b = P.batch[i];
        int col = min(max((int)(p.x / st), 0), W - 1);
        int row = min(max((int)(p.y / st), 0), H - 1);
        int lseg = b * HW + row * W + col;
        atomicAdd(&hist[lseg / tps], 1);
    }
    __syncthreads();
    for (int t = threadIdx.x; t < nt; t += 256) {
        int c = hist[t];
        if (c) atomicAdd(&tile_count[toff + t], c);
    }
}

// ---------------------------------------------------------------------------
// Prefix scan over 255 tile counts (single block)
// ---------------------------------------------------------------------------
__global__ __launch_bounds__(256) void p_scan(const int* __restrict__ tile_count,
                                              int* __restrict__ tile_base,
                                              int* __restrict__ tile_cursor)
{
    __shared__ int buf[256];
    int t = threadIdx.x;
    int v = (t < NTILES) ? tile_count[t] : 0;
    buf[t] = v;
    __syncthreads();
    int x = v;
    for (int off = 1; off < 256; off <<= 1) {
        int y = (t >= off) ? buf[t - off] : 0;
        __syncthreads();
        x += y;
        buf[t] = x;
        __syncthreads();
    }
    if (t < NTILES) { tile_base[t] = x - v; tile_cursor[t] = x - v; }
}

// ---------------------------------------------------------------------------
// Pass 2: scatter payloads into tile-sorted order.
// Sweep A: per-block per-tile counts (LDS). Reserve global ranges (1 atomic
// per block-tile). Sweep B: re-read points, LDS-cursor rank, write payload.
// ---------------------------------------------------------------------------
__global__ __launch_bounds__(256) void p2_scatter(Args a, int* __restrict__ tile_cursor,
                                                  float4* __restrict__ pay)
{
    __shared__ int tl[160];
    int lb; int s = block_scale(blockIdx.x, lb);
    int HW,W,H,tps,nt,toff,segoff,aoff; float st;
    scale_consts(s,HW,W,H,st,tps,nt,toff,segoff,aoff);
    const Ptrs& P = a.s[s];

    for (int t = threadIdx.x; t < nt; t += 256) tl[t] = 0;
    __syncthreads();

    int start = lb * P.chunk;
    int end   = min(start + P.chunk, P.n);
    const float2* pos = reinterpret_cast<const float2*>(P.pos);

    for (int i = start + (int)threadIdx.x; i < end; i += 256) {
        float2 p = pos[i];
        int b = P.batch[i];
        int col = min(max((int)(p.x / st), 0), W - 1);
        int row = min(max((int)(p.y / st), 0), H - 1);
        atomicAdd(&tl[(b * HW + row * W + col) / tps], 1);
    }
    __syncthreads();
    for (int t = threadIdx.x; t < nt; t += 256) {
        int c = tl[t];
        tl[t] = c ? atomicAdd(&tile_cursor[toff + t], c) : 0;
    }
    __syncthreads();

    const float4* reg4 = reinterpret_cast<const float4*>(P.reg);
    const float2* cls2 = reinterpret_cast<const float2*>(P.cls);
    for (int i = start + (int)threadIdx.x; i < end; i += 256) {
        float2 p = pos[i];
        int b = P.batch[i];
        int col = min(max((int)(p.x / st), 0), W - 1);
        int row = min(max((int)(p.y / st), 0), H - 1);
        int lseg = b * HW + row * W + col;
        int slot = atomicAdd(&tl[lseg / tps], 1);
        float4 r = reg4[i];
        float  o = P.obj[i];
        float2 c = cls2[i];
        pay[2 * (size_t)slot]     = r;
        pay[2 * (size_t)slot + 1] = make_float4(o, c.x, c.y, __int_as_float(segoff + lseg));
    }
}

// ---------------------------------------------------------------------------
// Pass 3: one block per tile — LDS accumulate (SoA: bank = local%32),
// then fused mean + sigmoid + YOLOX decode, direct output write.
// ---------------------------------------------------------------------------
__global__ __launch_bounds__(512) void p3_reduce(const float4* __restrict__ pay,
                                                 const int* __restrict__ tile_base,
                                                 const int* __restrict__ tile_count,
                                                 float* __restrict__ out)
{
    __shared__ float acc[8][1024];
    int t = blockIdx.x;
    int s = (t < 150) ? 0 : (t < 225) ? 1 : 2;
    int HW,W,H,tps,nt,toff,segoff,aoff; float st;
    scale_consts(s,HW,W,H,st,tps,nt,toff,segoff,aoff);
    int lt = t - toff;

    for (int c = 0; c < 8; ++c)
        for (int j = threadIdx.x; j < tps; j += 512) acc[c][j] = 0.f;
    __syncthreads();

    int base = tile_base[t];
    int cnt  = tile_count[t];
    int gseg0 = segoff + lt * tps;

    for (int i = base + (int)threadIdx.x; i < base + cnt; i += 512) {
        float4 ra = pay[2 * (size_t)i];
        float4 rb = pay[2 * (size_t)i + 1];
        int local = __float_as_int(rb.w) - gseg0;
        atomicAdd(&acc[0][local], ra.x);
        atomicAdd(&acc[1][local], ra.y);
        atomicAdd(&acc[2][local], ra.z);
        atomicAdd(&acc[3][local], ra.w);
        atomicAdd(&acc[4][local], rb.x);
        atomicAdd(&acc[5][local], rb.y);
        atomicAdd(&acc[6][local], rb.z);
        atomicAdd(&acc[7][local], 1.f);
    }
    __syncthreads();

    for (int j = threadIdx.x; j < tps; j += 512) {
        float cf  = acc[7][j];
        float inv = 1.f / fmaxf(cf, 1.f);
        int lseg = lt * tps + j;
        int b  = lseg / HW;
        int hw = lseg - b * HW;
        int row = hw / W, col = hw - row * W;
        float m0 = acc[0][j] * inv, m1 = acc[1][j] * inv;
        float m2 = acc[2][j] * inv, m3 = acc[3][j] * inv;
        float m4 = acc[4][j] * inv, m5 = acc[5][j] * inv, m6 = acc[6][j] * inv;
        float xx = (m0 + (float)col) * st;
        float yy = (m1 + (float)row) * st;
        float ww = expf(fminf(m2, 10.f)) * st;
        float hh = expf(fminf(m3, 10.f)) * st;
        float s4 = 1.f / (1.f + expf(-m4));
        float s5 = 1.f / (1.f + expf(-m5));
        float s6 = 1.f / (1.f + expf(-m6));
        float* ob = out + ((size_t)b * A_TOTAL + aoff + hw) * 7;
        ob[0] = xx; ob[1] = yy; ob[2] = ww; ob[3] = hh;
        ob[4] = s4; ob[5] = s5; ob[6] = s6;
    }
}

// ---------------------------------------------------------------------------
// Fallback path (round-1, known-correct): global-atomic scatter + finalize.
// Used only if ws_size can't hold the 32 B/point payload.
// ---------------------------------------------------------------------------
__global__ void fb_scatter(const float* __restrict__ cls,
                           const float* __restrict__ reg,
                           const float* __restrict__ obj,
                           const float* __restrict__ pos,
                           const int*   __restrict__ batch,
                           int n, int W, int H, float stride,
                           float* __restrict__ sums, float* __restrict__ counts)
{
    int i   = blockIdx.x * blockDim.x + threadIdx.x;
    int gsz = gridDim.x * blockDim.x;
    for (; i < n; i += gsz) {
        float2 p = reinterpret_cast<const float2*>(pos)[i];
        int b = batch[i];
        int col = min(max((int)(p.x / stride), 0), W - 1);
        int row = min(max((int)(p.y / stride), 0), H - 1);
        int seg = b * (H * W) + row * W + col;
        float4 r = reinterpret_cast<const float4*>(reg)[i];
        float  o = obj[i];
        float2 c = reinterpret_cast<const float2*>(cls)[i];
        float* sb = sums + (size_t)seg * 7;
        atomicAdd(sb + 0, r.x); atomicAdd(sb + 1, r.y);
        atomicAdd(sb + 2, r.z); atomicAdd(sb + 3, r.w);
        atomicAdd(sb + 4, o);   atomicAdd(sb + 5, c.x);
        atomicAdd(sb + 6, c.y); atomicAdd(counts + seg, 1.0f);
    }
}

__global__ void fb_finalize(const float* __restrict__ sums,
                            const float* __restrict__ counts,
                            float* __restrict__ out)
{
    int t = blockIdx.x * blockDim.x + threadIdx.x;
    if (t >= SEG_TOTAL) return;
    int b = t / A_TOTAL;
    int a = t - b * A_TOTAL;
    int hw, Wl, segbase; float stride;
    if (a < 4800)      { hw = a;        Wl = 80; stride = 3.f;  segbase = b * 4800; }
    else if (a < 6000) { hw = a - 4800; Wl = 40; stride = 6.f;  segbase = 153600 + b * 1200; }
    else               { hw = a - 6000; Wl = 20; stride = 12.f; segbase = 192000 + b * 300; }
    int seg = segbase + hw;
    int row = hw / Wl, col = hw - row * Wl;
    const float* sb = sums + (size_t)seg * 7;
    float inv = 1.0f / fmaxf(counts[seg], 1.0f);
    float m0 = sb[0]*inv, m1 = sb[1]*inv, m2 = sb[2]*inv, m3 = sb[3]*inv;
    float m4 = sb[4]*inv, m5 = sb[5]*inv, m6 = sb[6]*inv;
    float* ob = out + (size_t)t * 7;
    ob[0] = (m0 + (float)col) * stride;
    ob[1] = (m1 + (float)row) * stride;
    ob[2] = expf(fminf(m2, 10.f)) * stride;
    ob[3] = expf(fminf(m3, 10.f)) * stride;
    ob[4] = 1.f / (1.f + expf(-m4));
    ob[5] = 1.f / (1.f + expf(-m5));
    ob[6] = 1.f / (1.f + expf(-m6));
}

// ---------------------------------------------------------------------------
extern "C" void kernel_launch(void* const* d_in, const int* in_sizes, int n_in,
                              void* d_out, int out_size, void* d_ws, size_t ws_size,
                              hipStream_t stream)
{
    Args a;
    long long ntot = 0;
    for (int s = 0; s < 3; ++s) {
        a.s[s].cls   = (const float*)d_in[5*s + 0];
        a.s[s].reg   = (const float*)d_in[5*s + 1];
        a.s[s].obj   = (const float*)d_in[5*s + 2];
        a.s[s].pos   = (const float*)d_in[5*s + 3];
        a.s[s].batch = (const int*)  d_in[5*s + 4];
        a.s[s].n = in_sizes[5*s + 2];   // obj has 1 element per point
        ntot += a.s[s].n;
    }
    a.s[0].chunk = (a.s[0].n + NBLK0 - 1) / NBLK0;
    a.s[1].chunk = (a.s[1].n + NBLK1 - 1) / NBLK1;
    a.s[2].chunk = (a.s[2].n + NBLK2 - 1) / NBLK2;

    float* out = (float*)d_out;
    size_t need = 4096 + (size_t)ntot * 32;

    if (ws_size >= need) {
        int* tile_count  = (int*)d_ws;            // [256]
        int* tile_base   = tile_count + 256;      // [256]
        int* tile_cursor = tile_count + 512;      // [256]
        float4* pay = (float4*)((char*)d_ws + 4096);

        hipMemsetAsync(d_ws, 0, 1024, stream);    // zero tile_count each call
        p1_count  <<<NBLK_TOT, 256, 0, stream>>>(a, tile_count);
        p_scan    <<<1,        256, 0, stream>>>(tile_count, tile_base, tile_cursor);
        p2_scatter<<<NBLK_TOT, 256, 0, stream>>>(a, tile_cursor, pay);
        p3_reduce <<<NTILES,   512, 0, stream>>>(pay, tile_base, tile_count, out);
    } else {
        // Fallback: known-correct atomic path
        float* sums   = (float*)d_ws;                       // [SEG_TOTAL][7]
        float* counts = sums + (size_t)SEG_TOTAL * 7;       // [SEG_TOTAL]
        hipMemsetAsync(d_ws, 0, (size_t)SEG_TOTAL * 8 * sizeof(float), stream);
        const int   Ws[3] = {80, 40, 20};
        const int   Hs[3] = {60, 30, 15};
        const float Ss[3] = {3.f, 6.f, 12.f};
        const int   So[3] = {0, 153600, 192000};
        for (int s = 0; s < 3; ++s) {
            int n = a.s[s].n;
            int blocks = min((n + 255) / 256, 2048);
            fb_scatter<<<blocks, 256, 0, stream>>>(
                a.s[s].cls, a.s[s].reg, a.s[s].obj, a.s[s].pos, a.s[s].batch,
                n, Ws[s], Hs[s], Ss[s],
                sums + (size_t)So[s] * 7, counts + So[s]);
        }
        fb_finalize<<<(SEG_TOTAL + 255) / 256, 256, 0, stream>>>(sums, counts, out);
    }
}